// Round 1
// baseline (2043.503 us; speedup 1.0000x reference)
//
#include <hip/hip_runtime.h>

#define N_NODES 50000
#define IN_DIM  256
#define OUT_DIM 128

// ---------------------------------------------------------------------------
// Kernel 1: h[x_rows[e], :] += (x_vals[e] * mask[e]) * W[x_cols[e], :]
// One 64-lane wave per nonzero; each lane owns 2 of the 128 output dims
// (float2 load of W row, two f32 atomics into h).
// ---------------------------------------------------------------------------
__global__ void scatter_xw(const int* __restrict__ x_rows,
                           const int* __restrict__ x_cols,
                           const float* __restrict__ x_vals,
                           const float* __restrict__ drop_noise,
                           const float* __restrict__ W,
                           float* __restrict__ h,
                           int nnz) {
    int gid    = blockIdx.x * blockDim.x + threadIdx.x;
    int wave   = gid >> 6;
    int lane   = threadIdx.x & 63;
    int nwaves = (gridDim.x * blockDim.x) >> 6;

    for (int e = wave; e < nnz; e += nwaves) {
        int   row = x_rows[e];
        int   col = x_cols[e];
        // dropout_sparse with keep_prob = 1.0: mask = floor(1 + U[0,1)) == 1
        float v = x_vals[e] * floorf(1.0f + drop_noise[e]);

        const float2* Wrow = (const float2*)(W + (size_t)col * OUT_DIM);
        float2 w2 = Wrow[lane];

        float* hr = h + (size_t)row * OUT_DIM + 2 * lane;
        atomicAdd(hr + 0, v * w2.x);
        atomicAdd(hr + 1, v * w2.y);
    }
}

// ---------------------------------------------------------------------------
// Kernel 2: out[adj_rows[e], :] += adj_vals[e] * h[adj_cols[e], :]
// Same wave-per-edge structure.
// ---------------------------------------------------------------------------
__global__ void scatter_adj(const int* __restrict__ adj_rows,
                            const int* __restrict__ adj_cols,
                            const float* __restrict__ adj_vals,
                            const float* __restrict__ h,
                            float* __restrict__ out,
                            int ne) {
    int gid    = blockIdx.x * blockDim.x + threadIdx.x;
    int wave   = gid >> 6;
    int lane   = threadIdx.x & 63;
    int nwaves = (gridDim.x * blockDim.x) >> 6;

    for (int e = wave; e < ne; e += nwaves) {
        int   row = adj_rows[e];
        int   col = adj_cols[e];
        float w   = adj_vals[e];

        const float2* hrow = (const float2*)(h + (size_t)col * OUT_DIM);
        float2 h2 = hrow[lane];

        float* orow = out + (size_t)row * OUT_DIM + 2 * lane;
        atomicAdd(orow + 0, w * h2.x);
        atomicAdd(orow + 1, w * h2.y);
    }
}

// ---------------------------------------------------------------------------
// Kernel 3: in-place ReLU on out (float4-vectorized; out_size = 6.4M, /4 ok)
// ---------------------------------------------------------------------------
__global__ void relu_kernel(float* __restrict__ out, int n4) {
    int i      = blockIdx.x * blockDim.x + threadIdx.x;
    int stride = gridDim.x * blockDim.x;
    float4* o4 = (float4*)out;
    for (; i < n4; i += stride) {
        float4 v = o4[i];
        v.x = fmaxf(v.x, 0.0f);
        v.y = fmaxf(v.y, 0.0f);
        v.z = fmaxf(v.z, 0.0f);
        v.w = fmaxf(v.w, 0.0f);
        o4[i] = v;
    }
}

extern "C" void kernel_launch(void* const* d_in, const int* in_sizes, int n_in,
                              void* d_out, int out_size, void* d_ws, size_t ws_size,
                              hipStream_t stream) {
    const int*   x_rows     = (const int*)d_in[0];
    const int*   x_cols     = (const int*)d_in[1];
    const float* x_vals     = (const float*)d_in[2];
    const float* drop_noise = (const float*)d_in[3];
    const int*   adj_rows   = (const int*)d_in[4];
    const int*   adj_cols   = (const int*)d_in[5];
    const float* adj_vals   = (const float*)d_in[6];
    const float* W          = (const float*)d_in[7];

    float* out = (float*)d_out;
    float* h   = (float*)d_ws;   // N_NODES * OUT_DIM floats = 25.6 MB

    const int nnz = in_sizes[0];
    const int ne  = in_sizes[4];

    // zero accumulators (graph-capturable async memsets)
    hipMemsetAsync(h, 0, (size_t)N_NODES * OUT_DIM * sizeof(float), stream);
    hipMemsetAsync(out, 0, (size_t)out_size * sizeof(float), stream);

    // 4 waves per 256-thread block -> 4 nonzeros per block
    int blocks_x = (nnz + 3) / 4;
    scatter_xw<<<blocks_x, 256, 0, stream>>>(x_rows, x_cols, x_vals, drop_noise,
                                             W, h, nnz);

    int blocks_a = (ne + 3) / 4;
    scatter_adj<<<blocks_a, 256, 0, stream>>>(adj_rows, adj_cols, adj_vals,
                                              h, out, ne);

    int n4 = out_size / 4;
    int blocks_r = (n4 + 255) / 256;
    relu_kernel<<<blocks_r, 256, 0, stream>>>(out, n4);
}

// Round 2
// 584.360 us; speedup vs baseline: 3.4970x; 3.4970x over previous
//
#include <hip/hip_runtime.h>

#define N_NODES 50000
#define IN_DIM  256
#define OUT_DIM 128
#define OD2     64   // float2 elements per 128-dim row

// ---------------------------------------------------------------------------
// Histogram of row indices for both sparse matrices (counts zeroed by memset).
// ---------------------------------------------------------------------------
__global__ void hist_kernel(const int* __restrict__ xr, int nnz,
                            const int* __restrict__ ar, int ne,
                            int* __restrict__ cnt_x, int* __restrict__ cnt_a) {
    int i = blockIdx.x * blockDim.x + threadIdx.x;
    int stride = gridDim.x * blockDim.x;
    for (int e = i; e < nnz; e += stride) atomicAdd(&cnt_x[xr[e]], 1);
    for (int e = i; e < ne;  e += stride) atomicAdd(&cnt_a[ar[e]], 1);
}

// ---------------------------------------------------------------------------
// Exclusive scan over the two count arrays (block 0 -> x, block 1 -> adj).
// Writes row_ptr and a mutable cursor copy for the fill pass.
// ---------------------------------------------------------------------------
__global__ __launch_bounds__(1024) void scan_kernel(
        const int* __restrict__ cnt_x, int* __restrict__ ptr_x, int* __restrict__ cur_x,
        const int* __restrict__ cnt_a, int* __restrict__ ptr_a, int* __restrict__ cur_a,
        int n) {
    const int* c = (blockIdx.x == 0) ? cnt_x : cnt_a;
    int* p       = (blockIdx.x == 0) ? ptr_x : ptr_a;
    int* q       = (blockIdx.x == 0) ? cur_x : cur_a;

    __shared__ int buf[1024];
    __shared__ int carry;
    int tid = threadIdx.x;
    if (tid == 0) carry = 0;
    __syncthreads();

    for (int base = 0; base < n; base += 1024) {
        int v = (base + tid < n) ? c[base + tid] : 0;
        buf[tid] = v;
        __syncthreads();
        for (int off = 1; off < 1024; off <<= 1) {
            int t = (tid >= off) ? buf[tid - off] : 0;
            __syncthreads();
            buf[tid] += t;
            __syncthreads();
        }
        int excl = carry + buf[tid] - v;
        if (base + tid < n) { p[base + tid] = excl; q[base + tid] = excl; }
        __syncthreads();
        if (tid == 0) carry += buf[1023];
        __syncthreads();
    }
}

// ---------------------------------------------------------------------------
// Scatter nonzeros into CSR buckets (order within a row is arbitrary).
// Dropout mask applied here for the X matrix (keep_prob = 1.0, faithful).
// ---------------------------------------------------------------------------
__global__ void fill_kernel(const int* __restrict__ xr, const int* __restrict__ xc,
                            const float* __restrict__ xv, const float* __restrict__ dn, int nnz,
                            const int* __restrict__ ar, const int* __restrict__ ac,
                            const float* __restrict__ av, int ne,
                            int* __restrict__ cur_x, int* __restrict__ colx, float* __restrict__ valx,
                            int* __restrict__ cur_a, int* __restrict__ cola, float* __restrict__ vala) {
    int i = blockIdx.x * blockDim.x + threadIdx.x;
    int stride = gridDim.x * blockDim.x;
    for (int e = i; e < nnz; e += stride) {
        int r = xr[e];
        int p = atomicAdd(&cur_x[r], 1);
        colx[p] = xc[e];
        valx[p] = xv[e] * floorf(1.0f + dn[e]);   // mask == 1 computed faithfully
    }
    for (int e = i; e < ne; e += stride) {
        int r = ar[e];
        int p = atomicAdd(&cur_a[r], 1);
        cola[p] = ac[e];
        vala[p] = av[e];
    }
}

// ---------------------------------------------------------------------------
// Gather SpMM: one 64-lane wave per output row; lane owns dims {2l, 2l+1}.
// out[row] = sum_e val[e] * tab[col[e]]; optional fused ReLU.
// 2-way unroll so two gather loads are in flight per iteration.
// ---------------------------------------------------------------------------
template <bool RELU>
__global__ void spmm_gather(const int* __restrict__ ptr, const int* __restrict__ cnt,
                            const int* __restrict__ col, const float* __restrict__ val,
                            const float2* __restrict__ tab, float2* __restrict__ outm,
                            int nrows) {
    int wave = (blockIdx.x * blockDim.x + threadIdx.x) >> 6;
    int lane = threadIdx.x & 63;
    if (wave >= nrows) return;

    int s = ptr[wave];
    int end = s + cnt[wave];
    float2 acc = make_float2(0.0f, 0.0f);

    int e = s;
    for (; e + 1 < end; e += 2) {
        int   c0 = col[e],   c1 = col[e + 1];
        float v0 = val[e],   v1 = val[e + 1];
        float2 a = tab[(size_t)c0 * OD2 + lane];
        float2 b = tab[(size_t)c1 * OD2 + lane];
        acc.x += v0 * a.x + v1 * b.x;
        acc.y += v0 * a.y + v1 * b.y;
    }
    if (e < end) {
        int c0 = col[e];
        float v0 = val[e];
        float2 a = tab[(size_t)c0 * OD2 + lane];
        acc.x += v0 * a.x;
        acc.y += v0 * a.y;
    }
    if (RELU) {
        acc.x = fmaxf(acc.x, 0.0f);
        acc.y = fmaxf(acc.y, 0.0f);
    }
    outm[(size_t)wave * OD2 + lane] = acc;
}

extern "C" void kernel_launch(void* const* d_in, const int* in_sizes, int n_in,
                              void* d_out, int out_size, void* d_ws, size_t ws_size,
                              hipStream_t stream) {
    const int*   x_rows     = (const int*)d_in[0];
    const int*   x_cols     = (const int*)d_in[1];
    const float* x_vals     = (const float*)d_in[2];
    const float* drop_noise = (const float*)d_in[3];
    const int*   adj_rows   = (const int*)d_in[4];
    const int*   adj_cols   = (const int*)d_in[5];
    const float* adj_vals   = (const float*)d_in[6];
    const float* W          = (const float*)d_in[7];

    const int nnz = in_sizes[0];   // 800000
    const int ne  = in_sizes[4];   // 1600000

    // ---- workspace layout (all 16B-aligned) --------------------------------
    char* base = (char*)d_ws;
    float* h    = (float*)base;                         // 50000*128 f32 = 25.6 MB
    int* cnt_x  = (int*)(base + (size_t)N_NODES * OUT_DIM * sizeof(float));
    int* cnt_a  = cnt_x + N_NODES;
    int* ptr_x  = cnt_a + N_NODES;
    int* ptr_a  = ptr_x + N_NODES;
    int* cur_x  = ptr_a + N_NODES;
    int* cur_a  = cur_x + N_NODES;
    int*   colx = cur_a + N_NODES;                      // nnz ints
    float* valx = (float*)(colx + nnz);                 // nnz f32
    int*   cola = (int*)(valx + nnz);                   // ne ints
    float* vala = (float*)(cola + ne);                  // ne f32
    // total ~46 MB

    float* out = (float*)d_out;

    // zero the two count arrays (contiguous)
    hipMemsetAsync(cnt_x, 0, 2 * (size_t)N_NODES * sizeof(int), stream);

    // CSR build
    hist_kernel<<<(ne + 255) / 256, 256, 0, stream>>>(x_rows, nnz, adj_rows, ne,
                                                      cnt_x, cnt_a);
    scan_kernel<<<2, 1024, 0, stream>>>(cnt_x, ptr_x, cur_x,
                                        cnt_a, ptr_a, cur_a, N_NODES);
    fill_kernel<<<(ne + 255) / 256, 256, 0, stream>>>(
        x_rows, x_cols, x_vals, drop_noise, nnz,
        adj_rows, adj_cols, adj_vals, ne,
        cur_x, colx, valx, cur_a, cola, vala);

    // SpMM 1: h = X * W  (gather W rows; W is 128 KB -> cache-resident)
    int blocks = (N_NODES * 64) / 256;   // one wave per row, 4 waves/block
    spmm_gather<false><<<blocks, 256, 0, stream>>>(
        ptr_x, cnt_x, colx, valx, (const float2*)W, (float2*)h, N_NODES);

    // SpMM 2 + ReLU: out = relu(A * h)  (gather h rows; 25.6 MB -> L3-resident)
    spmm_gather<true><<<blocks, 256, 0, stream>>>(
        ptr_a, cnt_a, cola, vala, (const float2*)h, (float2*)out, N_NODES);
}